// Round 2
// baseline (1154.118 us; speedup 1.0000x reference)
//
#include <hip/hip_runtime.h>

// Fused 1->288ch 3x3 VALID conv + bias(full tensor) + ReLU, fp32.
// B=16, H=W=224, HOUT=WOUT=222, COUT=288.
// v3: no LDS, no barriers. Lane -> output column, wave -> 4 output rows,
// block = 4 waves x 4 channels. Every x load is 64 consecutive floats per
// wave-instruction (dense coalescing, L1/L2-resident); 18 loads cover the
// 6x3 input window for 4 vertical positions. Stores are dword, 256B/wave
// contiguous. Bias read once per thread, held in regs across all 16 batches.
// All waves independent -> stores stream at HBM write BW, no vmcnt(0) drains.

constexpr int Bn     = 16;
constexpr int COUT   = 288;
constexpr int Hin    = 224;
constexpr int Win    = 224;
constexpr int HOUT   = 222;
constexpr int WOUT   = 222;
constexpr int PLANE  = HOUT * WOUT;   // 49284
constexpr int XPLANE = Hin * Win;     // 50176

__global__ __launch_bounds__(256) void conv_bias_relu(
    const float* __restrict__ x,     // (16,1,224,224)
    const float* __restrict__ wgt,   // (288,1,3,3)
    const float* __restrict__ bias,  // (1,288,222,222)
    float* __restrict__ out)         // (16,288,222,222)
{
    const int tid  = threadIdx.x;
    const int lane = tid & 63;
    const int wid  = tid >> 6;

    const int c0  = blockIdx.x * 64;            // column tile base
    const int rb  = blockIdx.y * 16 + wid * 4;  // this wave's first out row
    const int co0 = blockIdx.z * 4;             // channel group base

    const int  c     = c0 + lane;
    const bool colok = (c < WOUT);
    const int  ceff  = colok ? c : (WOUT - 1);  // clamp: keep addrs in-bounds

    // 3x3 weights for 4 channels (block-uniform -> scalar loads)
    float wt[4][9];
    #pragma unroll
    for (int q = 0; q < 4; ++q)
        #pragma unroll
        for (int k = 0; k < 9; ++k)
            wt[q][k] = wgt[(co0 + q) * 9 + k];

    // x row offsets for the 6-row window (batch-invariant, clamped)
    int rofx[6];
    #pragma unroll
    for (int k = 0; k < 6; ++k)
        rofx[k] = min(rb + k, Hin - 1) * Win + ceff;

    // output row validity / clamped bias row offsets
    bool rowok[4];
    int  rofo[4];
    #pragma unroll
    for (int p = 0; p < 4; ++p) {
        rowok[p] = (rb + p) < HOUT;
        rofo[p]  = min(rb + p, HOUT - 1) * WOUT;
    }

    // bias: 16 values (4ch x 4rows), coalesced 256B/wave, read ONCE
    float bv[4][4];
    #pragma unroll
    for (int q = 0; q < 4; ++q)
        #pragma unroll
        for (int p = 0; p < 4; ++p)
            bv[q][p] = bias[(size_t)(co0 + q) * PLANE + rofo[p] + ceff];

    for (int b = 0; b < Bn; ++b) {
        const float* xb = x + b * XPLANE;

        // 6 rows x 3 col-offsets; each load = 64 consecutive floats per wave
        float xr[6][3];
        #pragma unroll
        for (int k = 0; k < 6; ++k)
            #pragma unroll
            for (int j = 0; j < 3; ++j)
                xr[k][j] = xb[rofx[k] + j];

        float acc[4][4];
        #pragma unroll
        for (int q = 0; q < 4; ++q)
            #pragma unroll
            for (int p = 0; p < 4; ++p)
                acc[q][p] = bv[q][p];

        #pragma unroll
        for (int p = 0; p < 4; ++p)
            #pragma unroll
            for (int kh = 0; kh < 3; ++kh)
                #pragma unroll
                for (int kw = 0; kw < 3; ++kw) {
                    const float xv = xr[p + kh][kw];
                    #pragma unroll
                    for (int q = 0; q < 4; ++q)
                        acc[q][p] = fmaf(wt[q][kh * 3 + kw], xv, acc[q][p]);
                }

        if (colok) {
            #pragma unroll
            for (int q = 0; q < 4; ++q) {
                float* ob = out + (size_t)(b * COUT + co0 + q) * PLANE + c;
                #pragma unroll
                for (int p = 0; p < 4; ++p)
                    if (rowok[p])
                        ob[(rb + p) * WOUT] = fmaxf(acc[q][p], 0.f);
            }
        }
    }
}

extern "C" void kernel_launch(void* const* d_in, const int* in_sizes, int n_in,
                              void* d_out, int out_size, void* d_ws, size_t ws_size,
                              hipStream_t stream) {
    const float* x    = (const float*)d_in[0];  // 16*1*224*224
    const float* w    = (const float*)d_in[1];  // 288*1*3*3
    const float* bias = (const float*)d_in[2];  // 1*288*222*222
    float* out        = (float*)d_out;          // 16*288*222*222

    dim3 block(256);
    dim3 grid((WOUT + 63) / 64,                 // 4 column tiles
              (HOUT + 15) / 16,                 // 14 row tiles (16 rows/block)
              COUT / 4);                        // 72 channel groups
    conv_bias_relu<<<grid, block, 0, stream>>>(x, w, bias, out);
}

// Round 3
// 992.601 us; speedup vs baseline: 1.1627x; 1.1627x over previous
//
#include <hip/hip_runtime.h>

// Fused 1->288ch 3x3 VALID conv + bias(full tensor) + ReLU, fp32.
// B=16, H=W=224, HOUT=WOUT=222, COUT=288.
// v4: flat-f4 mapping (aligned float4 stores, blocks own contiguous 4KB out
// segments -- v3 showed any other store layout pays HBM RMW on partial lines).
// x loads: 6 aligned dwordx4 per thread-batch (two 16B loads x 3 input rows),
// replacing v1's 36 strided scalar loads. Since f%4==0, wo0 is always EVEN,
// so the 6-col window [wo0..wo0+5] fits the aligned 8-float span
// [wo0&~3 .. +7]. Row-crossing threads (wo0==220 only) read the flat span
// that wraps into the next input row -- exactly the needed data at offsets
// 4..7. Phase/crossing handled by per-position +2 index shift via cndmask
// (static indexing, no scratch, no divergence). No LDS, no barriers.

constexpr int Bn     = 16;
constexpr int COUT   = 288;
constexpr int Hin    = 224;
constexpr int Win    = 224;
constexpr int HOUT   = 222;
constexpr int WOUT   = 222;
constexpr int PLANE  = HOUT * WOUT;   // 49284, divisible by 4
constexpr int NF4    = PLANE / 4;     // 12321 float4 groups per plane
constexpr int XPLANE = Hin * Win;     // 50176

__global__ __launch_bounds__(256) void conv_bias_relu(
    const float* __restrict__ x,     // (16,1,224,224)
    const float* __restrict__ wgt,   // (288,1,3,3)
    const float* __restrict__ bias,  // (1,288,222,222)
    float* __restrict__ out)         // (16,288,222,222)
{
    const int f4r    = blockIdx.x * 256 + threadIdx.x;
    const bool active = f4r < NF4;
    const int  f4    = active ? f4r : (NF4 - 1);   // clamp: keep addrs valid
    const int  f     = f4 * 4;
    const int  co0   = blockIdx.y * 4;

    const int ho0 = f / WOUT;                      // magic-mul, no div
    const int wo0 = f - ho0 * WOUT;                // always even
    const int wo0a = wo0 & ~3;
    const int xbase = ho0 * Win + wo0a;            // 16B-aligned span base

    // Per-position "+2 shift" flags:
    //  non-crossing: s_j = (wo0 & 2) for all j   (window starts at wo0a or wo0a+2)
    //  crossing (wo0==220, wo0&2==0): j>=2 lands on next row = span offsets 4..7
    const bool p2 = (wo0 & 2) != 0;
    const bool cr = (wo0 == 220);
    bool s[4];
    s[0] = p2; s[1] = p2; s[2] = p2 || cr; s[3] = p2 || cr;

    // 3x3 weights for this block's 4 channels (block-uniform -> scalar loads)
    float wt[4][9];
    #pragma unroll
    for (int q = 0; q < 4; ++q)
        #pragma unroll
        for (int k = 0; k < 9; ++k)
            wt[q][k] = wgt[(co0 + q) * 9 + k];

    // bias: one float4 per channel, read ONCE, reused for all 16 batches
    float4 bv[4];
    #pragma unroll
    for (int q = 0; q < 4; ++q)
        bv[q] = *reinterpret_cast<const float4*>(bias + (size_t)(co0 + q) * PLANE + f);

    for (int b = 0; b < Bn; ++b) {
        const float* xb = x + b * XPLANE + xbase;

        // 3 rows x 8 aligned floats: 6 dwordx4, dense 1KB/wave-instr
        float xsp[3][8];
        #pragma unroll
        for (int r = 0; r < 3; ++r) {
            const float4 a = *reinterpret_cast<const float4*>(xb + r * Win);
            const float4 c = *reinterpret_cast<const float4*>(xb + r * Win + 4);
            xsp[r][0] = a.x; xsp[r][1] = a.y; xsp[r][2] = a.z; xsp[r][3] = a.w;
            xsp[r][4] = c.x; xsp[r][5] = c.y; xsp[r][6] = c.z; xsp[r][7] = c.w;
        }

        float acc[4][4];
        #pragma unroll
        for (int q = 0; q < 4; ++q) {
            acc[q][0] = bv[q].x; acc[q][1] = bv[q].y;
            acc[q][2] = bv[q].z; acc[q][3] = bv[q].w;
        }

        #pragma unroll
        for (int j = 0; j < 4; ++j) {
            #pragma unroll
            for (int kh = 0; kh < 3; ++kh) {
                // window cols j+s*2 .. j+s*2+2 within the 8-float span
                const float a0 = s[j] ? xsp[kh][j + 2] : xsp[kh][j + 0];
                const float a1 = s[j] ? xsp[kh][j + 3] : xsp[kh][j + 1];
                const float a2 = s[j] ? xsp[kh][j + 4] : xsp[kh][j + 2];
                #pragma unroll
                for (int q = 0; q < 4; ++q) {
                    acc[q][j] = fmaf(wt[q][kh * 3 + 0], a0, acc[q][j]);
                    acc[q][j] = fmaf(wt[q][kh * 3 + 1], a1, acc[q][j]);
                    acc[q][j] = fmaf(wt[q][kh * 3 + 2], a2, acc[q][j]);
                }
            }
        }

        if (active) {
            #pragma unroll
            for (int q = 0; q < 4; ++q) {
                float4 o;
                o.x = fmaxf(acc[q][0], 0.f);
                o.y = fmaxf(acc[q][1], 0.f);
                o.z = fmaxf(acc[q][2], 0.f);
                o.w = fmaxf(acc[q][3], 0.f);
                *reinterpret_cast<float4*>(
                    out + (size_t)(b * COUT + co0 + q) * PLANE + f) = o;
            }
        }
    }
}

extern "C" void kernel_launch(void* const* d_in, const int* in_sizes, int n_in,
                              void* d_out, int out_size, void* d_ws, size_t ws_size,
                              hipStream_t stream) {
    const float* x    = (const float*)d_in[0];  // 16*1*224*224
    const float* w    = (const float*)d_in[1];  // 288*1*3*3
    const float* bias = (const float*)d_in[2];  // 1*288*222*222
    float* out        = (float*)d_out;          // 16*288*222*222

    dim3 block(256);
    dim3 grid((NF4 + 255) / 256, COUT / 4);     // 49 x 72
    conv_bias_relu<<<grid, block, 0, stream>>>(x, w, bias, out);
}